// Round 10
// baseline (248.421 us; speedup 1.0000x reference)
//
#include <hip/hip_runtime.h>
#include <hip/hip_bf16.h>

// Sizes (fixed by the problem)
#define BATCH 128
#define CCOND 16          // conditioning channels
#define CX    8           // flow channels
#define CIN0  24          // CCOND + CX
#define HID   32
#define LLEN  8192
#define NSTEP 2
#define PDIM  23          // 3K-1, K=8
#define POUT  184         // PDIM * CX
#define PSTR  48          // per-(b,c) param record stride in ws

// conv tiling: one wave = one independent 48-output window, no block barriers
#define WPW   48          // final outputs per wave
#define SROWS 56          // staged rows per wave: g in [gb-4, gb+52)
#define RSTR  40          // bf16 stride per row (80 B, 16B-aligned, 2-way banks)
#define LWORDS (SROWS * RSTR)   // 2240 bf16 per (single, in-place) buffer
#define GRIDX 43          // ceil(8192 / 192)

typedef __bf16 bf16x8 __attribute__((ext_vector_type(8)));
typedef __bf16 bf16x4 __attribute__((ext_vector_type(4)));
typedef float  f32x4  __attribute__((ext_vector_type(4)));

// wave-local LDS ordering fence (LDS ops complete in order per wave)
#define WAVE_SYNC() asm volatile("s_waitcnt lgkmcnt(0)" ::: "memory")

// DPP lane-move (VALU pipe) for the 16-lane reduce
template<int CTRL>
__device__ __forceinline__ float dpp_movf(float v) {
    return __int_as_float(
        __builtin_amdgcn_mov_dpp(__float_as_int(v), CTRL, 0xF, 0xF, true));
}
#define RROR1 0x121
#define RROR2 0x122
#define RROR4 0x124
#define RROR8 0x128

__device__ __forceinline__ unsigned short f2bf(float f) {
    unsigned u = __float_as_uint(f);
    return (unsigned short)((u + 0x7FFFu + ((u >> 16) & 1u)) >> 16);
}

// ---------------------------------------------------------------- util
// zeros hbar0|hbar1 (ws[0..8192)) and logdet[0..128)
__global__ void zero_kernel(float* __restrict__ ws, float* __restrict__ logdet) {
    int i = blockIdx.x * 256 + threadIdx.x;
    ws[i] = 0.f;
    if (i < BATCH) logdet[i] = 0.f;
}

// Pack conv weights into exact per-lane MFMA A-fragment order (bf16).
// wf[t][layer][s][mt][lane][j]; element = W[co = mt*16+(lane&15)]
//                                          [ci = (lane>>4)*8+j][koff = s]
__global__ void repack_frag_kernel(const float* __restrict__ w0,   // [2][32][24][3]
                                   const float* __restrict__ wh,   // [2][3][32][32][3]
                                   unsigned short* __restrict__ wf) {
    int i = blockIdx.x * 256 + threadIdx.x;     // 24576 total
    int j = i & 7, lane = (i >> 3) & 63, q = i >> 9;
    int mt = q & 1; q >>= 1;
    int s = q % 3;  q /= 3;
    int l = q & 3, t = q >> 2;
    int m = mt * 16 + (lane & 15);
    int ci = (lane >> 4) * 8 + j;
    float v;
    if (l == 0)
        v = (ci < CIN0) ? w0[((t * HID + m) * CIN0 + ci) * 3 + s] : 0.f;
    else
        v = wh[(((t * 3 + (l - 1)) * HID + m) * HID + ci) * 3 + s];
    wf[i] = f2bf(v);
}

// ---------------------------------------------------------------- fused convs
// One layer IN-PLACE over the wave's private window: rows [o-1,o+1] -> row o,
// o = starts[t] + prow. Safe because ALL fragment reads are issued (program
// order) before any write and same-wave LDS ops complete in order; overlap
// tiles recompute identical values (idempotent).
// EDGE: rows outside [0,L) forced to 0 (SAME zero padding); interior waves
// (97%) carry zero masking ops.
template<int NTL, int LAST, bool EDGE>
__device__ __forceinline__ void wconv_layer(
        __bf16* buf,
        const unsigned short* __restrict__ wl, const float* __restrict__ bp,
        const int (&starts)[NTL], int gb, int lane, float* __restrict__ vs) {
    const int prow = lane & 15, grp = lane >> 4;
    const int ci0 = grp * 8, co0 = grp * 4;

    bf16x8 af[3][2];
    #pragma unroll
    for (int s = 0; s < 3; ++s)
        #pragma unroll
        for (int mt = 0; mt < 2; ++mt)
            af[s][mt] = *reinterpret_cast<const bf16x8*>(
                wl + ((s * 2 + mt) << 9) + (lane << 3));
    f32x4 bias0 = *reinterpret_cast<const f32x4*>(bp + co0);
    f32x4 bias1 = *reinterpret_cast<const f32x4*>(bp + 16 + co0);

    // issue ALL fragment reads first; barrier pins them ahead of the MFMAs
    bf16x8 bfr[NTL][3];
    #pragma unroll
    for (int t = 0; t < NTL; ++t) {
        const int o = starts[t] + prow;
        #pragma unroll
        for (int tap = 0; tap < 3; ++tap)
            bfr[t][tap] = *reinterpret_cast<const bf16x8*>(
                &buf[(o + tap - 1) * RSTR + ci0]);
    }
    __builtin_amdgcn_sched_barrier(0);

    #pragma unroll
    for (int t = 0; t < NTL; ++t) {
        const int o = starts[t] + prow;
        f32x4 a0 = bias0, a1 = bias1;
        a0 = __builtin_amdgcn_mfma_f32_16x16x32_bf16(af[0][0], bfr[t][0], a0, 0, 0, 0);
        a1 = __builtin_amdgcn_mfma_f32_16x16x32_bf16(af[0][1], bfr[t][0], a1, 0, 0, 0);
        a0 = __builtin_amdgcn_mfma_f32_16x16x32_bf16(af[1][0], bfr[t][1], a0, 0, 0, 0);
        a1 = __builtin_amdgcn_mfma_f32_16x16x32_bf16(af[1][1], bfr[t][1], a1, 0, 0, 0);
        a0 = __builtin_amdgcn_mfma_f32_16x16x32_bf16(af[2][0], bfr[t][2], a0, 0, 0, 0);
        a1 = __builtin_amdgcn_mfma_f32_16x16x32_bf16(af[2][1], bfr[t][2], a1, 0, 0, 0);
        bool ok = true;
        if (EDGE) ok = (unsigned)(gb - 4 + o) < (unsigned)LLEN;
        #pragma unroll
        for (int r = 0; r < 4; ++r) {
            a0[r] = fmaxf(a0[r], 0.f);
            a1[r] = fmaxf(a1[r], 0.f);
            if (EDGE) { a0[r] = ok ? a0[r] : 0.f; a1[r] = ok ? a1[r] : 0.f; }
        }
        if (!LAST) {
            bf16x4 p0, p1;
            #pragma unroll
            for (int r = 0; r < 4; ++r) { p0[r] = (__bf16)a0[r]; p1[r] = (__bf16)a1[r]; }
            *reinterpret_cast<bf16x4*>(&buf[o * RSTR + co0]) = p0;
            *reinterpret_cast<bf16x4*>(&buf[o * RSTR + 16 + co0]) = p1;
        } else {
            #pragma unroll
            for (int r = 0; r < 4; ++r) { vs[r] += a0[r]; vs[4 + r] += a1[r]; }
        }
    }
}

template<bool EDGE>
__device__ __forceinline__ void conv_body(
        const float* __restrict__ cin, const float* __restrict__ xin,
        const unsigned short* __restrict__ wf,
        const float* __restrict__ b0p, const float* __restrict__ bhp,
        __bf16* buf,
        int b, int gb, int lane, float* __restrict__ vs) {
    // ---- stage: lane p = row p. 24 coalesced scalar loads ARE the transpose.
    if (lane < SROWS) {
        const int p = lane;
        int g = gb - 4 + p;
        int gc = g;
        bool ok = true;
        if (EDGE) { gc = min(max(g, 0), LLEN - 1); ok = (g == gc); }
        const float* cbp = cin + (size_t)b * CCOND * LLEN + gc;
        const float* xbp = xin + (size_t)b * CX * LLEN + gc;
        float v[CIN0];
        #pragma unroll
        for (int ch = 0; ch < CCOND; ++ch) v[ch] = cbp[(size_t)ch * LLEN];
        #pragma unroll
        for (int ch = 0; ch < CX; ++ch) v[CCOND + ch] = xbp[(size_t)ch * LLEN];
        if (EDGE) {
            #pragma unroll
            for (int ch = 0; ch < CIN0; ++ch) v[ch] = ok ? v[ch] : 0.f;
        }
        bf16x8 pk0, pk1, pk2;
        #pragma unroll
        for (int j = 0; j < 8; ++j) {
            pk0[j] = (__bf16)v[j];
            pk1[j] = (__bf16)v[8 + j];
            pk2[j] = (__bf16)v[16 + j];
        }
        *reinterpret_cast<bf16x8*>(&buf[p * RSTR])      = pk0;
        *reinterpret_cast<bf16x8*>(&buf[p * RSTR + 8])  = pk1;
        *reinterpret_cast<bf16x8*>(&buf[p * RSTR + 16]) = pk2;
        *reinterpret_cast<uint4*>(&buf[p * RSTR + 24])  = make_uint4(0, 0, 0, 0);
    }
    WAVE_SYNC();

    const int s0[4] = {1, 17, 33, 39};
    const int s1[4] = {2, 18, 34, 38};
    const int s2[4] = {3, 19, 35, 37};
    const int s3[3] = {4, 20, 36};
    wconv_layer<4, 0, EDGE>(buf, wf,        b0p,      s0, gb, lane, vs);
    WAVE_SYNC();
    wconv_layer<4, 0, EDGE>(buf, wf + 3072, bhp,      s1, gb, lane, vs);
    WAVE_SYNC();
    wconv_layer<4, 0, EDGE>(buf, wf + 6144, bhp + 32, s2, gb, lane, vs);
    WAVE_SYNC();
    wconv_layer<3, 1, EDGE>(buf, wf + 9216, bhp + 64, s3, gb, lane, vs);
}

__global__ __launch_bounds__(256, 6) void conv_kernel(
        const float* __restrict__ cin,   // [B][16][L]
        const float* __restrict__ xin,   // [B][8][L]
        const unsigned short* __restrict__ wf,  // this t: [4][3][2][64][8]
        const float* __restrict__ b0p,   // [32]   (this t)
        const float* __restrict__ bhp,   // [3][32](this t)
        float* __restrict__ hbar) {      // [B][32] sums (atomic)
    __shared__ __align__(16) __bf16 lds[4][LWORDS];
    __shared__ float psum[4][HID];

    const int tid = threadIdx.x;
    const int lane = tid & 63, wv = tid >> 6;
    const int b = blockIdx.y;
    const int gb = blockIdx.x * (4 * WPW) + wv * WPW;
    const int prow = lane & 15, grp = lane >> 4;

    __bf16* buf = &lds[wv][0];

    float vs[8] = {0.f, 0.f, 0.f, 0.f, 0.f, 0.f, 0.f, 0.f};
    const bool edge = (gb < 4) || (gb + SROWS - 4 > LLEN);
    if (edge)
        conv_body<true >(cin, xin, wf, b0p, bhp, buf, b, gb, lane, vs);
    else
        conv_body<false>(cin, xin, wf, b0p, bhp, buf, b, gb, lane, vs);

    // reduce vs over the 16 position-lanes via DPP row rotations (VALU pipe)
    #pragma unroll
    for (int r = 0; r < 8; ++r) {
        vs[r] += dpp_movf<RROR8>(vs[r]);
        vs[r] += dpp_movf<RROR4>(vs[r]);
        vs[r] += dpp_movf<RROR2>(vs[r]);
        vs[r] += dpp_movf<RROR1>(vs[r]);
    }
    const int co0 = grp * 4;
    if (prow == 0) {
        #pragma unroll
        for (int r = 0; r < 4; ++r) {
            psum[wv][co0 + r] = vs[r];
            psum[wv][16 + co0 + r] = vs[4 + r];
        }
    }
    __syncthreads();
    if (tid < HID) {
        float s = psum[0][tid] + psum[1][tid] + psum[2][tid] + psum[3][tid];
        atomicAdd(&hbar[b * HID + tid], s);
    }
}

// ---------------------------------------------------------------- spline prep
__device__ __forceinline__ float softplusf(float v) {
    return fmaxf(v, 0.f) + log1pf(expf(-fabsf(v)));
}

// One thread per (b,c): p = w_out * mean(h) + b_out, then knot arrays.
// w_out and this block's hbar slice staged in LDS (padded, conflict-free).
// Record layout (stride PSTR): cw[0..8], ch[9..17], w[18..25], h[26..33], d[34..42]
__global__ __launch_bounds__(256) void params_kernel(
        const float* __restrict__ hbar,   // [B][32] sums
        const float* __restrict__ w_out,  // [184][32] for this t
        const float* __restrict__ b_out,  // [184]
        float* __restrict__ params) {
    __shared__ float wsh[POUT][HID + 1];
    __shared__ float hsh[32][HID];
    const int tid = threadIdx.x;
    const float invL = 1.0f / (float)LLEN;
    for (int i = tid; i < POUT * HID; i += 256)
        wsh[i >> 5][i & 31] = w_out[i];
    for (int i = tid; i < 32 * HID; i += 256)
        hsh[i >> 5][i & 31] = hbar[blockIdx.x * 32 * HID + i] * invL;
    __syncthreads();

    int tg = blockIdx.x * 256 + tid;
    int bl = tid >> 3, c = tid & 7;

    float p[PDIM];
    #pragma unroll
    for (int j = 0; j < PDIM; j++) {
        int cp = c * PDIM + j;
        float acc = b_out[cp];
        #pragma unroll
        for (int h = 0; h < HID; h++) acc = fmaf(wsh[cp][h], hsh[bl][h], acc);
        p[j] = acc;
    }

    float* out = params + (size_t)tg * PSTR;

    // widths -> knot x positions
    {
        float mx = p[0];
        #pragma unroll
        for (int k = 1; k < 8; k++) mx = fmaxf(mx, p[k]);
        float e[8], se = 0.f;
        #pragma unroll
        for (int k = 0; k < 8; k++) { e[k] = expf(p[k] - mx); se += e[k]; }
        float inv = 1.f / se, cum = 0.f;
        float cw[9]; cw[0] = -3.f;
        #pragma unroll
        for (int k = 0; k < 8; k++) {
            float wk = 1e-3f + (1.f - 8e-3f) * (e[k] * inv);
            cum += wk;
            cw[k + 1] = 6.f * cum - 3.f;
        }
        #pragma unroll
        for (int k = 0; k < 9; k++) out[k] = cw[k];
        #pragma unroll
        for (int k = 0; k < 8; k++) out[18 + k] = cw[k + 1] - cw[k];
    }
    // heights -> knot y positions
    {
        float mx = p[8];
        #pragma unroll
        for (int k = 1; k < 8; k++) mx = fmaxf(mx, p[8 + k]);
        float e[8], se = 0.f;
        #pragma unroll
        for (int k = 0; k < 8; k++) { e[k] = expf(p[8 + k] - mx); se += e[k]; }
        float inv = 1.f / se, cum = 0.f;
        float ch[9]; ch[0] = -3.f;
        #pragma unroll
        for (int k = 0; k < 8; k++) {
            float hk = 1e-3f + (1.f - 8e-3f) * (e[k] * inv);
            cum += hk;
            ch[k + 1] = 6.f * cum - 3.f;
        }
        #pragma unroll
        for (int k = 0; k < 9; k++) out[9 + k] = ch[k];
        #pragma unroll
        for (int k = 0; k < 8; k++) out[26 + k] = ch[k + 1] - ch[k];
    }
    // derivatives (boundary = 1)
    out[34] = 1.f;
    #pragma unroll
    for (int k = 0; k < 7; k++) out[35 + k] = 1e-3f + softplusf(p[16 + k]);
    out[42] = 1.f;
}

// ---------------------------------------------------------------- RQS inverse
// 16 elements/thread (4x float4, hoisted loads). Params wave-uniform -> SGPRs;
// bin gather = branchless cndmask tree; raw v_log/v_sqrt/v_rcp.
__device__ __forceinline__ void rqs_elem(
        const float* cw, const float* chv, const float* wd,
        const float* hg, const float* dv,
        float y, float& ov, float& ldsum) {
    bool inside = fabsf(y) <= 3.0f;
    float yc = fminf(fmaxf(y, -3.f), 3.f);

    float icw = cw[0], iw = wd[0], ich = chv[0], ih = hg[0];
    float dk = dv[0], dk1 = dv[1];
    #pragma unroll
    for (int k = 1; k < 8; k++) {
        bool c = yc >= chv[k];
        icw = c ? cw[k]  : icw;
        iw  = c ? wd[k]  : iw;
        ich = c ? chv[k] : ich;
        ih  = c ? hg[k]  : ih;
        dk  = c ? dv[k]  : dk;
        dk1 = c ? dv[k + 1] : dk1;
    }
    float s  = ih * __builtin_amdgcn_rcpf(iw);
    float dy = yc - ich;
    float t1 = dk + dk1 - 2.f * s;
    float a  = ih * (s - dk) + dy * t1;
    float bq = ih * dk - dy * t1;
    float cq = -s * dy;
    float disc = fmaxf(bq * bq - 4.f * a * cq, 0.f);
    float den  = -bq - __builtin_amdgcn_sqrtf(disc);
    float root = (2.f * cq) * __builtin_amdgcn_rcpf(den);
    float om = 1.f - root;
    float outv  = fmaf(root, iw, icw);
    float denom = fmaf(t1 * root, om, s);
    float dnum  = s * s * (dk1 * root * root + 2.f * s * root * om + dk * om * om);
    float ld = (2.f * __builtin_amdgcn_logf(denom) - __builtin_amdgcn_logf(dnum))
               * 0.69314718055994531f;
    ov = inside ? outv : y;
    ldsum += inside ? ld : 0.f;
}

__global__ __launch_bounds__(256) void rqs_kernel(const float* __restrict__ params,
                                                  const float* __restrict__ xin,
                                                  float* __restrict__ xout,
                                                  float* __restrict__ logdet) {
    const int bc = blockIdx.y;
    const float* __restrict__ pp = params + (size_t)bc * PSTR;
    float cw[9], chv[9], wd[8], hg[8], dv[9];
    #pragma unroll
    for (int k = 0; k < 9; k++) cw[k] = pp[k];
    #pragma unroll
    for (int k = 0; k < 9; k++) chv[k] = pp[9 + k];
    #pragma unroll
    for (int k = 0; k < 8; k++) wd[k] = pp[18 + k];
    #pragma unroll
    for (int k = 0; k < 8; k++) hg[k] = pp[26 + k];
    #pragma unroll
    for (int k = 0; k < 9; k++) dv[k] = pp[34 + k];

    const int tid = threadIdx.x;
    size_t base = (size_t)bc * LLEN + (size_t)blockIdx.x * 4096 + (size_t)tid * 4;
    float4 y4[4];
    #pragma unroll
    for (int q = 0; q < 4; ++q)
        y4[q] = *reinterpret_cast<const float4*>(xin + base + q * 1024);

    float ldsum = 0.f;
    float4 o4[4];
    #pragma unroll
    for (int q = 0; q < 4; ++q) {
        rqs_elem(cw, chv, wd, hg, dv, y4[q].x, o4[q].x, ldsum);
        rqs_elem(cw, chv, wd, hg, dv, y4[q].y, o4[q].y, ldsum);
        rqs_elem(cw, chv, wd, hg, dv, y4[q].z, o4[q].z, ldsum);
        rqs_elem(cw, chv, wd, hg, dv, y4[q].w, o4[q].w, ldsum);
    }
    #pragma unroll
    for (int q = 0; q < 4; ++q)
        *reinterpret_cast<float4*>(xout + base + q * 1024) = o4[q];

    #pragma unroll
    for (int off = 32; off > 0; off >>= 1) ldsum += __shfl_xor(ldsum, off, 64);
    __shared__ float red[4];
    if ((tid & 63) == 0) red[tid >> 6] = ldsum;
    __syncthreads();
    if (tid == 0) {
        float sb = red[0] + red[1] + red[2] + red[3];
        atomicAdd(&logdet[bc >> 3], sb * (1.0f / (float)LLEN));
    }
}

// ---------------------------------------------------------------- launch
extern "C" void kernel_launch(void* const* d_in, const int* in_sizes, int n_in,
                              void* d_out, int out_size, void* d_ws, size_t ws_size,
                              hipStream_t stream) {
    const float* cin   = (const float*)d_in[1];
    const float* noise = (const float*)d_in[2];
    const float* w0    = (const float*)d_in[3];
    const float* b0    = (const float*)d_in[4];
    const float* wh    = (const float*)d_in[5];
    const float* bh    = (const float*)d_in[6];
    const float* w_out = (const float*)d_in[7];
    const float* b_out = (const float*)d_in[8];

    float* xout   = (float*)d_out;                       // [128*8*8192]
    float* logdet = xout + (size_t)BATCH * CX * LLEN;    // [128]

    float* ws     = (float*)d_ws;
    float* hbar0  = ws;                                  // 4096 floats
    float* hbar1  = ws + 4096;                           // 4096 floats
    float* params = ws + 8192;                           // 1024*48 floats
    unsigned short* wf = (unsigned short*)(ws + 8192 + 1024 * PSTR);  // 24576 ushorts

    zero_kernel<<<32, 256, 0, stream>>>(ws, logdet);     // hbar0|hbar1 + logdet
    repack_frag_kernel<<<96, 256, 0, stream>>>(w0, wh, wf);

    for (int t = 0; t < NSTEP; t++) {
        const float* xcur = (t == 0) ? noise : xout;
        float* hbar = (t == 0) ? hbar0 : hbar1;
        conv_kernel<<<dim3(GRIDX, BATCH), 256, 0, stream>>>(
            cin, xcur,
            wf + t * 12288, b0 + t * HID, bh + t * 3 * HID,
            hbar);
        params_kernel<<<BATCH * CX / 256, 256, 0, stream>>>(
            hbar, w_out + t * POUT * HID, b_out + t * POUT, params);
        rqs_kernel<<<dim3(LLEN / 4096, BATCH * CX), 256, 0, stream>>>(
            params, xcur, xout, logdet);
    }
}

// Round 11
// 237.133 us; speedup vs baseline: 1.0476x; 1.0476x over previous
//
#include <hip/hip_runtime.h>
#include <hip/hip_bf16.h>

// Sizes (fixed by the problem)
#define BATCH 128
#define CCOND 16          // conditioning channels
#define CX    8           // flow channels
#define CIN0  24          // CCOND + CX
#define HID   32
#define LLEN  8192
#define NSTEP 2
#define PDIM  23          // 3K-1, K=8
#define POUT  184         // PDIM * CX
#define PSTR  48          // per-(b,c) param record stride in ws

// conv tiling: one wave = one independent 32-output window, no block barriers
#define WPW   32          // final outputs per wave (multiple of 16: disjoint l3)
#define SROWS 40          // staged rows per wave: g in [gb-4, gb+36)
#define RSTR  40          // bf16 stride per row (80 B, 16B-aligned, 2-way banks)
#define LWORDS (SROWS * RSTR)   // 1600 bf16 per buffer
#define GRIDX 64          // 8192 / (4*32)

typedef __bf16 bf16x8 __attribute__((ext_vector_type(8)));
typedef __bf16 bf16x4 __attribute__((ext_vector_type(4)));
typedef float  f32x4  __attribute__((ext_vector_type(4)));

// wave-local LDS ordering fence (LDS ops complete in order per wave)
#define WAVE_SYNC() asm volatile("s_waitcnt lgkmcnt(0)" ::: "memory")

// DPP lane-move (VALU pipe) for the 16-lane reduce
template<int CTRL>
__device__ __forceinline__ float dpp_movf(float v) {
    return __int_as_float(
        __builtin_amdgcn_mov_dpp(__float_as_int(v), CTRL, 0xF, 0xF, true));
}
#define RROR1 0x121
#define RROR2 0x122
#define RROR4 0x124
#define RROR8 0x128

__device__ __forceinline__ unsigned short f2bf(float f) {
    unsigned u = __float_as_uint(f);
    return (unsigned short)((u + 0x7FFFu + ((u >> 16) & 1u)) >> 16);
}

// ---------------------------------------------------------------- util
// zeros hbar0|hbar1 (ws[0..8192)) and logdet[0..128)
__global__ void zero_kernel(float* __restrict__ ws, float* __restrict__ logdet) {
    int i = blockIdx.x * 256 + threadIdx.x;
    ws[i] = 0.f;
    if (i < BATCH) logdet[i] = 0.f;
}

// Pack conv weights into exact per-lane MFMA A-fragment order (bf16).
// wf[t][layer][s][mt][lane][j]; element = W[co = mt*16+(lane&15)]
//                                          [ci = (lane>>4)*8+j][koff = s]
__global__ void repack_frag_kernel(const float* __restrict__ w0,   // [2][32][24][3]
                                   const float* __restrict__ wh,   // [2][3][32][32][3]
                                   unsigned short* __restrict__ wf) {
    int i = blockIdx.x * 256 + threadIdx.x;     // 24576 total
    int j = i & 7, lane = (i >> 3) & 63, q = i >> 9;
    int mt = q & 1; q >>= 1;
    int s = q % 3;  q /= 3;
    int l = q & 3, t = q >> 2;
    int m = mt * 16 + (lane & 15);
    int ci = (lane >> 4) * 8 + j;
    float v;
    if (l == 0)
        v = (ci < CIN0) ? w0[((t * HID + m) * CIN0 + ci) * 3 + s] : 0.f;
    else
        v = wh[(((t * 3 + (l - 1)) * HID + m) * HID + ci) * 3 + s];
    wf[i] = f2bf(v);
}

// ---------------------------------------------------------------- fused convs
// One layer over the wave's private window: bin rows [o-1,o+1] -> bout row o,
// o = starts[t] + prow (overlapping tiles recompute rows idempotently).
// EDGE: rows outside [0,L) forced to 0 (SAME zero padding); interior waves
// carry zero masking ops.
template<int NTL, int LAST, bool EDGE>
__device__ __forceinline__ void wconv_layer(
        const __bf16* __restrict__ bin, __bf16* __restrict__ bout,
        const unsigned short* __restrict__ wl, const float* __restrict__ bp,
        const int (&starts)[NTL], int gb, int lane, float* __restrict__ vs) {
    const int prow = lane & 15, grp = lane >> 4;
    const int ci0 = grp * 8, co0 = grp * 4;

    bf16x8 af[3][2];
    #pragma unroll
    for (int s = 0; s < 3; ++s)
        #pragma unroll
        for (int mt = 0; mt < 2; ++mt)
            af[s][mt] = *reinterpret_cast<const bf16x8*>(
                wl + ((s * 2 + mt) << 9) + (lane << 3));
    f32x4 bias0 = *reinterpret_cast<const f32x4*>(bp + co0);
    f32x4 bias1 = *reinterpret_cast<const f32x4*>(bp + 16 + co0);

    // issue ALL fragment reads first; barrier pins them ahead of the MFMAs
    bf16x8 bfr[NTL][3];
    #pragma unroll
    for (int t = 0; t < NTL; ++t) {
        const int o = starts[t] + prow;
        #pragma unroll
        for (int tap = 0; tap < 3; ++tap)
            bfr[t][tap] = *reinterpret_cast<const bf16x8*>(
                &bin[(o + tap - 1) * RSTR + ci0]);
    }
    __builtin_amdgcn_sched_barrier(0);

    #pragma unroll
    for (int t = 0; t < NTL; ++t) {
        const int o = starts[t] + prow;
        f32x4 a0 = bias0, a1 = bias1;
        a0 = __builtin_amdgcn_mfma_f32_16x16x32_bf16(af[0][0], bfr[t][0], a0, 0, 0, 0);
        a1 = __builtin_amdgcn_mfma_f32_16x16x32_bf16(af[0][1], bfr[t][0], a1, 0, 0, 0);
        a0 = __builtin_amdgcn_mfma_f32_16x16x32_bf16(af[1][0], bfr[t][1], a0, 0, 0, 0);
        a1 = __builtin_amdgcn_mfma_f32_16x16x32_bf16(af[1][1], bfr[t][1], a1, 0, 0, 0);
        a0 = __builtin_amdgcn_mfma_f32_16x16x32_bf16(af[2][0], bfr[t][2], a0, 0, 0, 0);
        a1 = __builtin_amdgcn_mfma_f32_16x16x32_bf16(af[2][1], bfr[t][2], a1, 0, 0, 0);
        bool ok = true;
        if (EDGE) ok = (unsigned)(gb - 4 + o) < (unsigned)LLEN;
        #pragma unroll
        for (int r = 0; r < 4; ++r) {
            a0[r] = fmaxf(a0[r], 0.f);
            a1[r] = fmaxf(a1[r], 0.f);
            if (EDGE) { a0[r] = ok ? a0[r] : 0.f; a1[r] = ok ? a1[r] : 0.f; }
        }
        if (!LAST) {
            bf16x4 p0, p1;
            #pragma unroll
            for (int r = 0; r < 4; ++r) { p0[r] = (__bf16)a0[r]; p1[r] = (__bf16)a1[r]; }
            *reinterpret_cast<bf16x4*>(&bout[o * RSTR + co0]) = p0;
            *reinterpret_cast<bf16x4*>(&bout[o * RSTR + 16 + co0]) = p1;
        } else {
            #pragma unroll
            for (int r = 0; r < 4; ++r) { vs[r] += a0[r]; vs[4 + r] += a1[r]; }
        }
    }
}

template<bool EDGE>
__device__ __forceinline__ void conv_body(
        const float* __restrict__ cin, const float* __restrict__ xin,
        const unsigned short* __restrict__ wf,
        const float* __restrict__ b0p, const float* __restrict__ bhp,
        __bf16* __restrict__ bufA, __bf16* __restrict__ bufB,
        int b, int gb, int lane, float* __restrict__ vs) {
    // ---- stage: lane p = row p. 24 coalesced scalar loads ARE the transpose.
    if (lane < SROWS) {
        const int p = lane;
        int g = gb - 4 + p;
        int gc = g;
        bool ok = true;
        if (EDGE) { gc = min(max(g, 0), LLEN - 1); ok = (g == gc); }
        const float* cbp = cin + (size_t)b * CCOND * LLEN + gc;
        const float* xbp = xin + (size_t)b * CX * LLEN + gc;
        float v[CIN0];
        #pragma unroll
        for (int ch = 0; ch < CCOND; ++ch) v[ch] = cbp[(size_t)ch * LLEN];
        #pragma unroll
        for (int ch = 0; ch < CX; ++ch) v[CCOND + ch] = xbp[(size_t)ch * LLEN];
        if (EDGE) {
            #pragma unroll
            for (int ch = 0; ch < CIN0; ++ch) v[ch] = ok ? v[ch] : 0.f;
        }
        bf16x8 pk0, pk1, pk2;
        #pragma unroll
        for (int j = 0; j < 8; ++j) {
            pk0[j] = (__bf16)v[j];
            pk1[j] = (__bf16)v[8 + j];
            pk2[j] = (__bf16)v[16 + j];
        }
        *reinterpret_cast<bf16x8*>(&bufA[p * RSTR])      = pk0;
        *reinterpret_cast<bf16x8*>(&bufA[p * RSTR + 8])  = pk1;
        *reinterpret_cast<bf16x8*>(&bufA[p * RSTR + 16]) = pk2;
        *reinterpret_cast<uint4*>(&bufA[p * RSTR + 24])  = make_uint4(0, 0, 0, 0);
    }
    WAVE_SYNC();

    const int s0[3] = {1, 17, 23};
    const int s1[3] = {2, 18, 22};
    const int s2[3] = {3, 19, 21};
    const int s3[2] = {4, 20};
    wconv_layer<3, 0, EDGE>(bufA, bufB, wf,        b0p,      s0, gb, lane, vs);
    WAVE_SYNC();
    wconv_layer<3, 0, EDGE>(bufB, bufA, wf + 3072, bhp,      s1, gb, lane, vs);
    WAVE_SYNC();
    wconv_layer<3, 0, EDGE>(bufA, bufB, wf + 6144, bhp + 32, s2, gb, lane, vs);
    WAVE_SYNC();
    wconv_layer<2, 1, EDGE>(bufB, bufA, wf + 9216, bhp + 64, s3, gb, lane, vs);
}

__global__ __launch_bounds__(256, 6) void conv_kernel(
        const float* __restrict__ cin,   // [B][16][L]
        const float* __restrict__ xin,   // [B][8][L]
        const unsigned short* __restrict__ wf,  // this t: [4][3][2][64][8]
        const float* __restrict__ b0p,   // [32]   (this t)
        const float* __restrict__ bhp,   // [3][32](this t)
        float* __restrict__ hbar) {      // [B][32] sums (atomic)
    __shared__ __align__(16) __bf16 lds[4][2][LWORDS];
    __shared__ float psum[4][HID];

    const int tid = threadIdx.x;
    const int lane = tid & 63, wv = tid >> 6;
    const int b = blockIdx.y;
    const int gb = blockIdx.x * (4 * WPW) + wv * WPW;
    const int prow = lane & 15, grp = lane >> 4;

    __bf16* bufA = &lds[wv][0][0];
    __bf16* bufB = &lds[wv][1][0];

    float vs[8] = {0.f, 0.f, 0.f, 0.f, 0.f, 0.f, 0.f, 0.f};
    const bool edge = (gb < 4) || (gb + SROWS - 4 > LLEN);
    if (edge)
        conv_body<true >(cin, xin, wf, b0p, bhp, bufA, bufB, b, gb, lane, vs);
    else
        conv_body<false>(cin, xin, wf, b0p, bhp, bufA, bufB, b, gb, lane, vs);

    // reduce vs over the 16 position-lanes via DPP row rotations (VALU pipe)
    #pragma unroll
    for (int r = 0; r < 8; ++r) {
        vs[r] += dpp_movf<RROR8>(vs[r]);
        vs[r] += dpp_movf<RROR4>(vs[r]);
        vs[r] += dpp_movf<RROR2>(vs[r]);
        vs[r] += dpp_movf<RROR1>(vs[r]);
    }
    const int co0 = grp * 4;
    if (prow == 0) {
        #pragma unroll
        for (int r = 0; r < 4; ++r) {
            psum[wv][co0 + r] = vs[r];
            psum[wv][16 + co0 + r] = vs[4 + r];
        }
    }
    __syncthreads();
    if (tid < HID) {
        float s = psum[0][tid] + psum[1][tid] + psum[2][tid] + psum[3][tid];
        atomicAdd(&hbar[b * HID + tid], s);
    }
}

// ---------------------------------------------------------------- spline prep
__device__ __forceinline__ float softplusf(float v) {
    return fmaxf(v, 0.f) + log1pf(expf(-fabsf(v)));
}

// One thread per (b,c): p = w_out * mean(h) + b_out, then knot arrays.
// w_out and this block's hbar slice staged in LDS (padded, conflict-free).
// Record layout (stride PSTR): cw[0..8], ch[9..17], w[18..25], h[26..33], d[34..42]
__global__ __launch_bounds__(256) void params_kernel(
        const float* __restrict__ hbar,   // [B][32] sums
        const float* __restrict__ w_out,  // [184][32] for this t
        const float* __restrict__ b_out,  // [184]
        float* __restrict__ params) {
    __shared__ float wsh[POUT][HID + 1];
    __shared__ float hsh[32][HID];
    const int tid = threadIdx.x;
    const float invL = 1.0f / (float)LLEN;
    for (int i = tid; i < POUT * HID; i += 256)
        wsh[i >> 5][i & 31] = w_out[i];
    for (int i = tid; i < 32 * HID; i += 256)
        hsh[i >> 5][i & 31] = hbar[blockIdx.x * 32 * HID + i] * invL;
    __syncthreads();

    int tg = blockIdx.x * 256 + tid;
    int bl = tid >> 3, c = tid & 7;

    float p[PDIM];
    #pragma unroll
    for (int j = 0; j < PDIM; j++) {
        int cp = c * PDIM + j;
        float acc = b_out[cp];
        #pragma unroll
        for (int h = 0; h < HID; h++) acc = fmaf(wsh[cp][h], hsh[bl][h], acc);
        p[j] = acc;
    }

    float* out = params + (size_t)tg * PSTR;

    // widths -> knot x positions
    {
        float mx = p[0];
        #pragma unroll
        for (int k = 1; k < 8; k++) mx = fmaxf(mx, p[k]);
        float e[8], se = 0.f;
        #pragma unroll
        for (int k = 0; k < 8; k++) { e[k] = expf(p[k] - mx); se += e[k]; }
        float inv = 1.f / se, cum = 0.f;
        float cw[9]; cw[0] = -3.f;
        #pragma unroll
        for (int k = 0; k < 8; k++) {
            float wk = 1e-3f + (1.f - 8e-3f) * (e[k] * inv);
            cum += wk;
            cw[k + 1] = 6.f * cum - 3.f;
        }
        #pragma unroll
        for (int k = 0; k < 9; k++) out[k] = cw[k];
        #pragma unroll
        for (int k = 0; k < 8; k++) out[18 + k] = cw[k + 1] - cw[k];
    }
    // heights -> knot y positions
    {
        float mx = p[8];
        #pragma unroll
        for (int k = 1; k < 8; k++) mx = fmaxf(mx, p[8 + k]);
        float e[8], se = 0.f;
        #pragma unroll
        for (int k = 0; k < 8; k++) { e[k] = expf(p[8 + k] - mx); se += e[k]; }
        float inv = 1.f / se, cum = 0.f;
        float ch[9]; ch[0] = -3.f;
        #pragma unroll
        for (int k = 0; k < 8; k++) {
            float hk = 1e-3f + (1.f - 8e-3f) * (e[k] * inv);
            cum += hk;
            ch[k + 1] = 6.f * cum - 3.f;
        }
        #pragma unroll
        for (int k = 0; k < 9; k++) out[9 + k] = ch[k];
        #pragma unroll
        for (int k = 0; k < 8; k++) out[26 + k] = ch[k + 1] - ch[k];
    }
    // derivatives (boundary = 1)
    out[34] = 1.f;
    #pragma unroll
    for (int k = 0; k < 7; k++) out[35 + k] = 1e-3f + softplusf(p[16 + k]);
    out[42] = 1.f;
}

// ---------------------------------------------------------------- RQS inverse
// 16 elements/thread (4x float4, hoisted loads). Params wave-uniform -> SGPRs;
// bin gather = branchless cndmask tree; raw v_log/v_sqrt/v_rcp.
__device__ __forceinline__ void rqs_elem(
        const float* cw, const float* chv, const float* wd,
        const float* hg, const float* dv,
        float y, float& ov, float& ldsum) {
    bool inside = fabsf(y) <= 3.0f;
    float yc = fminf(fmaxf(y, -3.f), 3.f);

    float icw = cw[0], iw = wd[0], ich = chv[0], ih = hg[0];
    float dk = dv[0], dk1 = dv[1];
    #pragma unroll
    for (int k = 1; k < 8; k++) {
        bool c = yc >= chv[k];
        icw = c ? cw[k]  : icw;
        iw  = c ? wd[k]  : iw;
        ich = c ? chv[k] : ich;
        ih  = c ? hg[k]  : ih;
        dk  = c ? dv[k]  : dk;
        dk1 = c ? dv[k + 1] : dk1;
    }
    float s  = ih * __builtin_amdgcn_rcpf(iw);
    float dy = yc - ich;
    float t1 = dk + dk1 - 2.f * s;
    float a  = ih * (s - dk) + dy * t1;
    float bq = ih * dk - dy * t1;
    float cq = -s * dy;
    float disc = fmaxf(bq * bq - 4.f * a * cq, 0.f);
    float den  = -bq - __builtin_amdgcn_sqrtf(disc);
    float root = (2.f * cq) * __builtin_amdgcn_rcpf(den);
    float om = 1.f - root;
    float outv  = fmaf(root, iw, icw);
    float denom = fmaf(t1 * root, om, s);
    float dnum  = s * s * (dk1 * root * root + 2.f * s * root * om + dk * om * om);
    float ld = (2.f * __builtin_amdgcn_logf(denom) - __builtin_amdgcn_logf(dnum))
               * 0.69314718055994531f;
    ov = inside ? outv : y;
    ldsum += inside ? ld : 0.f;
}

__global__ __launch_bounds__(256) void rqs_kernel(const float* __restrict__ params,
                                                  const float* __restrict__ xin,
                                                  float* __restrict__ xout,
                                                  float* __restrict__ logdet) {
    const int bc = blockIdx.y;
    const float* __restrict__ pp = params + (size_t)bc * PSTR;
    float cw[9], chv[9], wd[8], hg[8], dv[9];
    #pragma unroll
    for (int k = 0; k < 9; k++) cw[k] = pp[k];
    #pragma unroll
    for (int k = 0; k < 9; k++) chv[k] = pp[9 + k];
    #pragma unroll
    for (int k = 0; k < 8; k++) wd[k] = pp[18 + k];
    #pragma unroll
    for (int k = 0; k < 8; k++) hg[k] = pp[26 + k];
    #pragma unroll
    for (int k = 0; k < 9; k++) dv[k] = pp[34 + k];

    const int tid = threadIdx.x;
    size_t base = (size_t)bc * LLEN + (size_t)blockIdx.x * 4096 + (size_t)tid * 4;
    float4 y4[4];
    #pragma unroll
    for (int q = 0; q < 4; ++q)
        y4[q] = *reinterpret_cast<const float4*>(xin + base + q * 1024);

    float ldsum = 0.f;
    float4 o4[4];
    #pragma unroll
    for (int q = 0; q < 4; ++q) {
        rqs_elem(cw, chv, wd, hg, dv, y4[q].x, o4[q].x, ldsum);
        rqs_elem(cw, chv, wd, hg, dv, y4[q].y, o4[q].y, ldsum);
        rqs_elem(cw, chv, wd, hg, dv, y4[q].z, o4[q].z, ldsum);
        rqs_elem(cw, chv, wd, hg, dv, y4[q].w, o4[q].w, ldsum);
    }
    #pragma unroll
    for (int q = 0; q < 4; ++q)
        *reinterpret_cast<float4*>(xout + base + q * 1024) = o4[q];

    #pragma unroll
    for (int off = 32; off > 0; off >>= 1) ldsum += __shfl_xor(ldsum, off, 64);
    __shared__ float red[4];
    if ((tid & 63) == 0) red[tid >> 6] = ldsum;
    __syncthreads();
    if (tid == 0) {
        float sb = red[0] + red[1] + red[2] + red[3];
        atomicAdd(&logdet[bc >> 3], sb * (1.0f / (float)LLEN));
    }
}

// ---------------------------------------------------------------- launch
extern "C" void kernel_launch(void* const* d_in, const int* in_sizes, int n_in,
                              void* d_out, int out_size, void* d_ws, size_t ws_size,
                              hipStream_t stream) {
    const float* cin   = (const float*)d_in[1];
    const float* noise = (const float*)d_in[2];
    const float* w0    = (const float*)d_in[3];
    const float* b0    = (const float*)d_in[4];
    const float* wh    = (const float*)d_in[5];
    const float* bh    = (const float*)d_in[6];
    const float* w_out = (const float*)d_in[7];
    const float* b_out = (const float*)d_in[8];

    float* xout   = (float*)d_out;                       // [128*8*8192]
    float* logdet = xout + (size_t)BATCH * CX * LLEN;    // [128]

    float* ws     = (float*)d_ws;
    float* hbar0  = ws;                                  // 4096 floats
    float* hbar1  = ws + 4096;                           // 4096 floats
    float* params = ws + 8192;                           // 1024*48 floats
    unsigned short* wf = (unsigned short*)(ws + 8192 + 1024 * PSTR);  // 24576 ushorts

    zero_kernel<<<32, 256, 0, stream>>>(ws, logdet);     // hbar0|hbar1 + logdet
    repack_frag_kernel<<<96, 256, 0, stream>>>(w0, wh, wf);

    for (int t = 0; t < NSTEP; t++) {
        const float* xcur = (t == 0) ? noise : xout;
        float* hbar = (t == 0) ? hbar0 : hbar1;
        conv_kernel<<<dim3(GRIDX, BATCH), 256, 0, stream>>>(
            cin, xcur,
            wf + t * 12288, b0 + t * HID, bh + t * 3 * HID,
            hbar);
        params_kernel<<<BATCH * CX / 256, 256, 0, stream>>>(
            hbar, w_out + t * POUT * HID, b_out + t * POUT, params);
        rqs_kernel<<<dim3(LLEN / 4096, BATCH * CX), 256, 0, stream>>>(
            params, xcur, xout, logdet);
    }
}

// Round 12
// 163.601 us; speedup vs baseline: 1.5185x; 1.4495x over previous
//
#include <hip/hip_runtime.h>
#include <hip/hip_bf16.h>

// Sizes (fixed by the problem)
#define BATCH 128
#define CCOND 16          // conditioning channels
#define CX    8           // flow channels
#define CIN0  24          // CCOND + CX
#define HID   32
#define LLEN  8192
#define NSTEP 2
#define PDIM  23          // 3K-1, K=8
#define POUT  184         // PDIM * CX
#define PSTR  48          // per-(b,c) param record stride in ws

// conv tiling: one wave = one independent 48-output window, no block barriers
#define WPW   48          // final outputs per wave
#define SROWS 56          // staged rows per wave: g in [gb-4, gb+52)
#define RSTR  40          // bf16 stride per row (80 B, 16B-aligned, 2-way banks)
#define LWORDS (SROWS * RSTR)   // 2240 bf16 per buffer
#define GRIDX 43          // ceil(8192 / 192)

typedef __bf16 bf16x8 __attribute__((ext_vector_type(8)));
typedef __bf16 bf16x4 __attribute__((ext_vector_type(4)));
typedef float  f32x4  __attribute__((ext_vector_type(4)));

// wave-local LDS ordering fence (DS pipe is in-order per wave)
#define WAVE_SYNC() asm volatile("s_waitcnt lgkmcnt(0)" ::: "memory")

// DPP lane-move (VALU pipe) for the 16-lane reduce
template<int CTRL>
__device__ __forceinline__ float dpp_movf(float v) {
    return __int_as_float(
        __builtin_amdgcn_mov_dpp(__float_as_int(v), CTRL, 0xF, 0xF, true));
}
#define RROR1 0x121
#define RROR2 0x122
#define RROR4 0x124
#define RROR8 0x128

__device__ __forceinline__ unsigned short f2bf(float f) {
    unsigned u = __float_as_uint(f);
    return (unsigned short)((u + 0x7FFFu + ((u >> 16) & 1u)) >> 16);
}

// ---------------------------------------------------------------- util
// zeros hbar0|hbar1 (ws[0..8192)) and logdet[0..128)
__global__ void zero_kernel(float* __restrict__ ws, float* __restrict__ logdet) {
    int i = blockIdx.x * 256 + threadIdx.x;
    ws[i] = 0.f;
    if (i < BATCH) logdet[i] = 0.f;
}

// Pack conv weights into exact per-lane MFMA A-fragment order (bf16).
// wf[t][layer][s][mt][lane][j]; element = W[co = mt*16+(lane&15)]
//                                          [ci = (lane>>4)*8+j][koff = s]
__global__ void repack_frag_kernel(const float* __restrict__ w0,   // [2][32][24][3]
                                   const float* __restrict__ wh,   // [2][3][32][32][3]
                                   unsigned short* __restrict__ wf) {
    int i = blockIdx.x * 256 + threadIdx.x;     // 24576 total
    int j = i & 7, lane = (i >> 3) & 63, q = i >> 9;
    int mt = q & 1; q >>= 1;
    int s = q % 3;  q /= 3;
    int l = q & 3, t = q >> 2;
    int m = mt * 16 + (lane & 15);
    int ci = (lane >> 4) * 8 + j;
    float v;
    if (l == 0)
        v = (ci < CIN0) ? w0[((t * HID + m) * CIN0 + ci) * 3 + s] : 0.f;
    else
        v = wh[(((t * 3 + (l - 1)) * HID + m) * HID + ci) * 3 + s];
    wf[i] = f2bf(v);
}

// ---------------------------------------------------------------- fused convs
// One layer over the wave's private window: bin rows [o-1,o+1] -> bout row o,
// o = starts[t] + prow (overlapping tiles recompute rows idempotently).
// EDGE: rows whose global g is outside [0,L) forced to 0 (SAME zero padding);
// interior waves (97%) skip all masking ops.
template<int NTL, int LAST, bool EDGE>
__device__ __forceinline__ void wconv_layer(
        const __bf16* __restrict__ bin, __bf16* __restrict__ bout,
        const unsigned short* __restrict__ wl, const float* __restrict__ bp,
        const int (&starts)[NTL], int gb, int lane, float* __restrict__ vs) {
    const int prow = lane & 15, grp = lane >> 4;
    const int ci0 = grp * 8, co0 = grp * 4;

    bf16x8 af[3][2];
    #pragma unroll
    for (int s = 0; s < 3; ++s)
        #pragma unroll
        for (int mt = 0; mt < 2; ++mt)
            af[s][mt] = *reinterpret_cast<const bf16x8*>(
                wl + ((s * 2 + mt) << 9) + (lane << 3));
    f32x4 bias0 = *reinterpret_cast<const f32x4*>(bp + co0);
    f32x4 bias1 = *reinterpret_cast<const f32x4*>(bp + 16 + co0);

    // issue ALL fragment reads first; barrier pins them ahead of the MFMAs
    bf16x8 bfr[NTL][3];
    #pragma unroll
    for (int t = 0; t < NTL; ++t) {
        const int o = starts[t] + prow;
        #pragma unroll
        for (int tap = 0; tap < 3; ++tap)
            bfr[t][tap] = *reinterpret_cast<const bf16x8*>(
                &bin[(o + tap - 1) * RSTR + ci0]);
    }
    __builtin_amdgcn_sched_barrier(0);

    #pragma unroll
    for (int t = 0; t < NTL; ++t) {
        const int o = starts[t] + prow;
        f32x4 a0 = bias0, a1 = bias1;
        a0 = __builtin_amdgcn_mfma_f32_16x16x32_bf16(af[0][0], bfr[t][0], a0, 0, 0, 0);
        a1 = __builtin_amdgcn_mfma_f32_16x16x32_bf16(af[0][1], bfr[t][0], a1, 0, 0, 0);
        a0 = __builtin_amdgcn_mfma_f32_16x16x32_bf16(af[1][0], bfr[t][1], a0, 0, 0, 0);
        a1 = __builtin_amdgcn_mfma_f32_16x16x32_bf16(af[1][1], bfr[t][1], a1, 0, 0, 0);
        a0 = __builtin_amdgcn_mfma_f32_16x16x32_bf16(af[2][0], bfr[t][2], a0, 0, 0, 0);
        a1 = __builtin_amdgcn_mfma_f32_16x16x32_bf16(af[2][1], bfr[t][2], a1, 0, 0, 0);
        bool ok = true;
        if (EDGE) ok = (unsigned)(gb - 4 + o) < (unsigned)LLEN;
        #pragma unroll
        for (int r = 0; r < 4; ++r) {
            a0[r] = fmaxf(a0[r], 0.f);
            a1[r] = fmaxf(a1[r], 0.f);
            if (EDGE) { a0[r] = ok ? a0[r] : 0.f; a1[r] = ok ? a1[r] : 0.f; }
        }
        if (!LAST) {
            bf16x4 p0, p1;
            #pragma unroll
            for (int r = 0; r < 4; ++r) { p0[r] = (__bf16)a0[r]; p1[r] = (__bf16)a1[r]; }
            *reinterpret_cast<bf16x4*>(&bout[o * RSTR + co0]) = p0;
            *reinterpret_cast<bf16x4*>(&bout[o * RSTR + 16 + co0]) = p1;
        } else {
            #pragma unroll
            for (int r = 0; r < 4; ++r) { vs[r] += a0[r]; vs[4 + r] += a1[r]; }
        }
    }
}

template<bool EDGE>
__device__ __forceinline__ void conv_body(
        const float* __restrict__ cin, const float* __restrict__ xin,
        const unsigned short* __restrict__ wf,
        const float* __restrict__ b0p, const float* __restrict__ bhp,
        __bf16* __restrict__ bufA, __bf16* __restrict__ bufB,
        int b, int gb, int lane, float* __restrict__ vs) {
    // ---- stage: lane p = row p. 24 coalesced scalar loads ARE the transpose.
    if (lane < SROWS) {
        const int p = lane;
        int g = gb - 4 + p;
        int gc = g;
        bool ok = true;
        if (EDGE) { gc = min(max(g, 0), LLEN - 1); ok = (g == gc); }
        const float* cbp = cin + (size_t)b * CCOND * LLEN + gc;
        const float* xbp = xin + (size_t)b * CX * LLEN + gc;
        float v[CIN0];
        #pragma unroll
        for (int ch = 0; ch < CCOND; ++ch) v[ch] = cbp[(size_t)ch * LLEN];
        #pragma unroll
        for (int ch = 0; ch < CX; ++ch) v[CCOND + ch] = xbp[(size_t)ch * LLEN];
        if (EDGE) {
            #pragma unroll
            for (int ch = 0; ch < CIN0; ++ch) v[ch] = ok ? v[ch] : 0.f;
        }
        bf16x8 pk0, pk1, pk2;
        #pragma unroll
        for (int j = 0; j < 8; ++j) {
            pk0[j] = (__bf16)v[j];
            pk1[j] = (__bf16)v[8 + j];
            pk2[j] = (__bf16)v[16 + j];
        }
        *reinterpret_cast<bf16x8*>(&bufA[p * RSTR])      = pk0;
        *reinterpret_cast<bf16x8*>(&bufA[p * RSTR + 8])  = pk1;
        *reinterpret_cast<bf16x8*>(&bufA[p * RSTR + 16]) = pk2;
        *reinterpret_cast<uint4*>(&bufA[p * RSTR + 24])  = make_uint4(0, 0, 0, 0);
    }
    WAVE_SYNC();

    const int s0[4] = {1, 17, 33, 39};
    const int s1[4] = {2, 18, 34, 38};
    const int s2[4] = {3, 19, 35, 37};
    const int s3[3] = {4, 20, 36};
    wconv_layer<4, 0, EDGE>(bufA, bufB, wf,        b0p,      s0, gb, lane, vs);
    WAVE_SYNC();
    wconv_layer<4, 0, EDGE>(bufB, bufA, wf + 3072, bhp,      s1, gb, lane, vs);
    WAVE_SYNC();
    wconv_layer<4, 0, EDGE>(bufA, bufB, wf + 6144, bhp + 32, s2, gb, lane, vs);
    WAVE_SYNC();
    wconv_layer<3, 1, EDGE>(bufB, bufA, wf + 9216, bhp + 64, s3, gb, lane, vs);
}

__global__ __launch_bounds__(256, 4) void conv_kernel(
        const float* __restrict__ cin,   // [B][16][L]
        const float* __restrict__ xin,   // [B][8][L]
        const unsigned short* __restrict__ wf,  // this t: [4][3][2][64][8]
        const float* __restrict__ b0p,   // [32]   (this t)
        const float* __restrict__ bhp,   // [3][32](this t)
        float* __restrict__ hbar) {      // [B][32] sums (atomic)
    __shared__ __align__(16) __bf16 lds[4][2][LWORDS];
    __shared__ float psum[4][HID];

    const int tid = threadIdx.x;
    const int lane = tid & 63, wv = tid >> 6;
    const int b = blockIdx.y;
    const int gb = blockIdx.x * (4 * WPW) + wv * WPW;
    const int prow = lane & 15, grp = lane >> 4;

    __bf16* bufA = &lds[wv][0][0];
    __bf16* bufB = &lds[wv][1][0];

    float vs[8] = {0.f, 0.f, 0.f, 0.f, 0.f, 0.f, 0.f, 0.f};
    const bool edge = (gb < 4) || (gb + SROWS - 4 > LLEN);
    if (edge)
        conv_body<true >(cin, xin, wf, b0p, bhp, bufA, bufB, b, gb, lane, vs);
    else
        conv_body<false>(cin, xin, wf, b0p, bhp, bufA, bufB, b, gb, lane, vs);

    // reduce vs over the 16 position-lanes via DPP row rotations (VALU pipe)
    #pragma unroll
    for (int r = 0; r < 8; ++r) {
        vs[r] += dpp_movf<RROR8>(vs[r]);
        vs[r] += dpp_movf<RROR4>(vs[r]);
        vs[r] += dpp_movf<RROR2>(vs[r]);
        vs[r] += dpp_movf<RROR1>(vs[r]);
    }
    const int co0 = grp * 4;
    if (prow == 0) {
        #pragma unroll
        for (int r = 0; r < 4; ++r) {
            psum[wv][co0 + r] = vs[r];
            psum[wv][16 + co0 + r] = vs[4 + r];
        }
    }
    __syncthreads();
    if (tid < HID) {
        float s = psum[0][tid] + psum[1][tid] + psum[2][tid] + psum[3][tid];
        atomicAdd(&hbar[b * HID + tid], s);
    }
}

// ---------------------------------------------------------------- spline prep
__device__ __forceinline__ float softplusf(float v) {
    return fmaxf(v, 0.f) + log1pf(expf(-fabsf(v)));
}

// One thread per (b,c): p = w_out * mean(h) + b_out, then knot arrays.
// w_out and this block's hbar slice staged in LDS (padded, conflict-free).
// Record layout (stride PSTR): cw[0..8], ch[9..17], w[18..25], h[26..33], d[34..42]
__global__ __launch_bounds__(256) void params_kernel(
        const float* __restrict__ hbar,   // [B][32] sums
        const float* __restrict__ w_out,  // [184][32] for this t
        const float* __restrict__ b_out,  // [184]
        float* __restrict__ params) {
    __shared__ float wsh[POUT][HID + 1];
    __shared__ float hsh[32][HID];
    const int tid = threadIdx.x;
    const float invL = 1.0f / (float)LLEN;
    for (int i = tid; i < POUT * HID; i += 256)
        wsh[i >> 5][i & 31] = w_out[i];
    for (int i = tid; i < 32 * HID; i += 256)
        hsh[i >> 5][i & 31] = hbar[blockIdx.x * 32 * HID + i] * invL;
    __syncthreads();

    int tg = blockIdx.x * 256 + tid;
    int bl = tid >> 3, c = tid & 7;

    float p[PDIM];
    #pragma unroll
    for (int j = 0; j < PDIM; j++) {
        int cp = c * PDIM + j;
        float acc = b_out[cp];
        #pragma unroll
        for (int h = 0; h < HID; h++) acc = fmaf(wsh[cp][h], hsh[bl][h], acc);
        p[j] = acc;
    }

    float* out = params + (size_t)tg * PSTR;

    // widths -> knot x positions
    {
        float mx = p[0];
        #pragma unroll
        for (int k = 1; k < 8; k++) mx = fmaxf(mx, p[k]);
        float e[8], se = 0.f;
        #pragma unroll
        for (int k = 0; k < 8; k++) { e[k] = expf(p[k] - mx); se += e[k]; }
        float inv = 1.f / se, cum = 0.f;
        float cw[9]; cw[0] = -3.f;
        #pragma unroll
        for (int k = 0; k < 8; k++) {
            float wk = 1e-3f + (1.f - 8e-3f) * (e[k] * inv);
            cum += wk;
            cw[k + 1] = 6.f * cum - 3.f;
        }
        #pragma unroll
        for (int k = 0; k < 9; k++) out[k] = cw[k];
        #pragma unroll
        for (int k = 0; k < 8; k++) out[18 + k] = cw[k + 1] - cw[k];
    }
    // heights -> knot y positions
    {
        float mx = p[8];
        #pragma unroll
        for (int k = 1; k < 8; k++) mx = fmaxf(mx, p[8 + k]);
        float e[8], se = 0.f;
        #pragma unroll
        for (int k = 0; k < 8; k++) { e[k] = expf(p[8 + k] - mx); se += e[k]; }
        float inv = 1.f / se, cum = 0.f;
        float ch[9]; ch[0] = -3.f;
        #pragma unroll
        for (int k = 0; k < 8; k++) {
            float hk = 1e-3f + (1.f - 8e-3f) * (e[k] * inv);
            cum += hk;
            ch[k + 1] = 6.f * cum - 3.f;
        }
        #pragma unroll
        for (int k = 0; k < 9; k++) out[9 + k] = ch[k];
        #pragma unroll
        for (int k = 0; k < 8; k++) out[26 + k] = ch[k + 1] - ch[k];
    }
    // derivatives (boundary = 1)
    out[34] = 1.f;
    #pragma unroll
    for (int k = 0; k < 7; k++) out[35 + k] = 1e-3f + softplusf(p[16 + k]);
    out[42] = 1.f;
}

// ---------------------------------------------------------------- RQS inverse
// 16 elements/thread (4x float4, hoisted loads). Params wave-uniform -> SGPRs;
// bin gather = branchless cndmask tree; raw v_log/v_sqrt/v_rcp.
__device__ __forceinline__ void rqs_elem(
        const float* cw, const float* chv, const float* wd,
        const float* hg, const float* dv,
        float y, float& ov, float& ldsum) {
    bool inside = fabsf(y) <= 3.0f;
    float yc = fminf(fmaxf(y, -3.f), 3.f);

    float icw = cw[0], iw = wd[0], ich = chv[0], ih = hg[0];
    float dk = dv[0], dk1 = dv[1];
    #pragma unroll
    for (int k = 1; k < 8; k++) {
        bool c = yc >= chv[k];
        icw = c ? cw[k]  : icw;
        iw  = c ? wd[k]  : iw;
        ich = c ? chv[k] : ich;
        ih  = c ? hg[k]  : ih;
        dk  = c ? dv[k]  : dk;
        dk1 = c ? dv[k + 1] : dk1;
    }
    float s  = ih * __builtin_amdgcn_rcpf(iw);
    float dy = yc - ich;
    float t1 = dk + dk1 - 2.f * s;
    float a  = ih * (s - dk) + dy * t1;
    float bq = ih * dk - dy * t1;
    float cq = -s * dy;
    float disc = fmaxf(bq * bq - 4.f * a * cq, 0.f);
    float den  = -bq - __builtin_amdgcn_sqrtf(disc);
    float root = (2.f * cq) * __builtin_amdgcn_rcpf(den);
    float om = 1.f - root;
    float outv  = fmaf(root, iw, icw);
    float denom = fmaf(t1 * root, om, s);
    float dnum  = s * s * (dk1 * root * root + 2.f * s * root * om + dk * om * om);
    float ld = (2.f * __builtin_amdgcn_logf(denom) - __builtin_amdgcn_logf(dnum))
               * 0.69314718055994531f;
    ov = inside ? outv : y;
    ldsum += inside ? ld : 0.f;
}

__global__ __launch_bounds__(256) void rqs_kernel(const float* __restrict__ params,
                                                  const float* __restrict__ xin,
                                                  float* __restrict__ xout,
                                                  float* __restrict__ logdet) {
    const int bc = blockIdx.y;
    const float* __restrict__ pp = params + (size_t)bc * PSTR;
    float cw[9], chv[9], wd[8], hg[8], dv[9];
    #pragma unroll
    for (int k = 0; k < 9; k++) cw[k] = pp[k];
    #pragma unroll
    for (int k = 0; k < 9; k++) chv[k] = pp[9 + k];
    #pragma unroll
    for (int k = 0; k < 8; k++) wd[k] = pp[18 + k];
    #pragma unroll
    for (int k = 0; k < 8; k++) hg[k] = pp[26 + k];
    #pragma unroll
    for (int k = 0; k < 9; k++) dv[k] = pp[34 + k];

    const int tid = threadIdx.x;
    size_t base = (size_t)bc * LLEN + (size_t)blockIdx.x * 4096 + (size_t)tid * 4;
    float4 y4[4];
    #pragma unroll
    for (int q = 0; q < 4; ++q)
        y4[q] = *reinterpret_cast<const float4*>(xin + base + q * 1024);

    float ldsum = 0.f;
    float4 o4[4];
    #pragma unroll
    for (int q = 0; q < 4; ++q) {
        rqs_elem(cw, chv, wd, hg, dv, y4[q].x, o4[q].x, ldsum);
        rqs_elem(cw, chv, wd, hg, dv, y4[q].y, o4[q].y, ldsum);
        rqs_elem(cw, chv, wd, hg, dv, y4[q].z, o4[q].z, ldsum);
        rqs_elem(cw, chv, wd, hg, dv, y4[q].w, o4[q].w, ldsum);
    }
    #pragma unroll
    for (int q = 0; q < 4; ++q)
        *reinterpret_cast<float4*>(xout + base + q * 1024) = o4[q];

    #pragma unroll
    for (int off = 32; off > 0; off >>= 1) ldsum += __shfl_xor(ldsum, off, 64);
    __shared__ float red[4];
    if ((tid & 63) == 0) red[tid >> 6] = ldsum;
    __syncthreads();
    if (tid == 0) {
        float sb = red[0] + red[1] + red[2] + red[3];
        atomicAdd(&logdet[bc >> 3], sb * (1.0f / (float)LLEN));
    }
}

// ---------------------------------------------------------------- launch
extern "C" void kernel_launch(void* const* d_in, const int* in_sizes, int n_in,
                              void* d_out, int out_size, void* d_ws, size_t ws_size,
                              hipStream_t stream) {
    const float* cin   = (const float*)d_in[1];
    const float* noise = (const float*)d_in[2];
    const float* w0    = (const float*)d_in[3];
    const float* b0    = (const float*)d_in[4];
    const float* wh    = (const float*)d_in[5];
    const float* bh    = (const float*)d_in[6];
    const float* w_out = (const float*)d_in[7];
    const float* b_out = (const float*)d_in[8];

    float* xout   = (float*)d_out;                       // [128*8*8192]
    float* logdet = xout + (size_t)BATCH * CX * LLEN;    // [128]

    float* ws     = (float*)d_ws;
    float* hbar0  = ws;                                  // 4096 floats
    float* hbar1  = ws + 4096;                           // 4096 floats
    float* params = ws + 8192;                           // 1024*48 floats
    unsigned short* wf = (unsigned short*)(ws + 8192 + 1024 * PSTR);  // 24576 ushorts

    zero_kernel<<<32, 256, 0, stream>>>(ws, logdet);     // hbar0|hbar1 + logdet
    repack_frag_kernel<<<96, 256, 0, stream>>>(w0, wh, wf);

    for (int t = 0; t < NSTEP; t++) {
        const float* xcur = (t == 0) ? noise : xout;
        float* hbar = (t == 0) ? hbar0 : hbar1;
        conv_kernel<<<dim3(GRIDX, BATCH), 256, 0, stream>>>(
            cin, xcur,
            wf + t * 12288, b0 + t * HID, bh + t * 3 * HID,
            hbar);
        params_kernel<<<BATCH * CX / 256, 256, 0, stream>>>(
            hbar, w_out + t * POUT * HID, b_out + t * POUT, params);
        rqs_kernel<<<dim3(LLEN / 4096, BATCH * CX), 256, 0, stream>>>(
            params, xcur, xout, logdet);
    }
}

// Round 13
// 149.752 us; speedup vs baseline: 1.6589x; 1.0925x over previous
//
#include <hip/hip_runtime.h>
#include <hip/hip_bf16.h>

// Sizes (fixed by the problem)
#define BATCH 128
#define CCOND 16          // conditioning channels
#define CX    8           // flow channels
#define CIN0  24          // CCOND + CX
#define HID   32
#define LLEN  8192
#define NSTEP 2
#define PDIM  23          // 3K-1, K=8
#define POUT  184         // PDIM * CX

// conv tiling: one wave = one independent 48-output window, no block barriers
#define WPW   48          // final outputs per wave
#define SROWS 56          // staged rows per wave: g in [gb-4, gb+52)
#define RSTR  40          // bf16 stride per row (80 B, 16B-aligned, 2-way banks)
#define LWORDS (SROWS * RSTR)   // 2240 bf16 per buffer
#define GRIDX 43          // ceil(8192 / 192)

typedef __bf16 bf16x8 __attribute__((ext_vector_type(8)));
typedef __bf16 bf16x4 __attribute__((ext_vector_type(4)));
typedef float  f32x4  __attribute__((ext_vector_type(4)));

// wave-local LDS ordering fence (DS pipe is in-order per wave)
#define WAVE_SYNC() asm volatile("s_waitcnt lgkmcnt(0)" ::: "memory")

// DPP lane-move (VALU pipe) for the 16-lane reduce
template<int CTRL>
__device__ __forceinline__ float dpp_movf(float v) {
    return __int_as_float(
        __builtin_amdgcn_mov_dpp(__float_as_int(v), CTRL, 0xF, 0xF, true));
}
#define RROR1 0x121
#define RROR2 0x122
#define RROR4 0x124
#define RROR8 0x128

__device__ __forceinline__ unsigned short f2bf(float f) {
    unsigned u = __float_as_uint(f);
    return (unsigned short)((u + 0x7FFFu + ((u >> 16) & 1u)) >> 16);
}

// ---------------------------------------------------------------- init
// One kernel: zero hbar0|hbar1 + logdet, AND pack conv weights into per-lane
// MFMA A-fragment order. wf[t][layer][s][mt][lane][j];
// element = W[co = mt*16+(lane&15)][ci = (lane>>4)*8+j][koff = s]
__global__ void init_kernel(const float* __restrict__ w0,   // [2][32][24][3]
                            const float* __restrict__ wh,   // [2][3][32][32][3]
                            unsigned short* __restrict__ wf,
                            float* __restrict__ ws,         // hbar0|hbar1 (8192)
                            float* __restrict__ logdet) {
    int i = blockIdx.x * 256 + threadIdx.x;     // 96 blocks = 24576
    if (i < 8192) ws[i] = 0.f;
    if (i < BATCH) logdet[i] = 0.f;

    int j = i & 7, lane = (i >> 3) & 63, q = i >> 9;
    int mt = q & 1; q >>= 1;
    int s = q % 3;  q /= 3;
    int l = q & 3, t = q >> 2;
    int m = mt * 16 + (lane & 15);
    int ci = (lane >> 4) * 8 + j;
    float v;
    if (l == 0)
        v = (ci < CIN0) ? w0[((t * HID + m) * CIN0 + ci) * 3 + s] : 0.f;
    else
        v = wh[(((t * 3 + (l - 1)) * HID + m) * HID + ci) * 3 + s];
    wf[i] = f2bf(v);
}

// ---------------------------------------------------------------- fused convs
// One layer over the wave's private window: bin rows [o-1,o+1] -> bout row o,
// o = starts[t] + prow (overlapping tiles recompute rows idempotently).
// EDGE: rows whose global g is outside [0,L) forced to 0 (SAME zero padding);
// interior waves (97%) skip all masking ops.
template<int NTL, int LAST, bool EDGE>
__device__ __forceinline__ void wconv_layer(
        const __bf16* __restrict__ bin, __bf16* __restrict__ bout,
        const unsigned short* __restrict__ wl, const float* __restrict__ bp,
        const int (&starts)[NTL], int gb, int lane, float* __restrict__ vs) {
    const int prow = lane & 15, grp = lane >> 4;
    const int ci0 = grp * 8, co0 = grp * 4;

    bf16x8 af[3][2];
    #pragma unroll
    for (int s = 0; s < 3; ++s)
        #pragma unroll
        for (int mt = 0; mt < 2; ++mt)
            af[s][mt] = *reinterpret_cast<const bf16x8*>(
                wl + ((s * 2 + mt) << 9) + (lane << 3));
    f32x4 bias0 = *reinterpret_cast<const f32x4*>(bp + co0);
    f32x4 bias1 = *reinterpret_cast<const f32x4*>(bp + 16 + co0);

    // issue ALL fragment reads first; barrier pins them ahead of the MFMAs
    bf16x8 bfr[NTL][3];
    #pragma unroll
    for (int t = 0; t < NTL; ++t) {
        const int o = starts[t] + prow;
        #pragma unroll
        for (int tap = 0; tap < 3; ++tap)
            bfr[t][tap] = *reinterpret_cast<const bf16x8*>(
                &bin[(o + tap - 1) * RSTR + ci0]);
    }
    __builtin_amdgcn_sched_barrier(0);

    #pragma unroll
    for (int t = 0; t < NTL; ++t) {
        const int o = starts[t] + prow;
        f32x4 a0 = bias0, a1 = bias1;
        a0 = __builtin_amdgcn_mfma_f32_16x16x32_bf16(af[0][0], bfr[t][0], a0, 0, 0, 0);
        a1 = __builtin_amdgcn_mfma_f32_16x16x32_bf16(af[0][1], bfr[t][0], a1, 0, 0, 0);
        a0 = __builtin_amdgcn_mfma_f32_16x16x32_bf16(af[1][0], bfr[t][1], a0, 0, 0, 0);
        a1 = __builtin_amdgcn_mfma_f32_16x16x32_bf16(af[1][1], bfr[t][1], a1, 0, 0, 0);
        a0 = __builtin_amdgcn_mfma_f32_16x16x32_bf16(af[2][0], bfr[t][2], a0, 0, 0, 0);
        a1 = __builtin_amdgcn_mfma_f32_16x16x32_bf16(af[2][1], bfr[t][2], a1, 0, 0, 0);
        bool ok = true;
        if (EDGE) ok = (unsigned)(gb - 4 + o) < (unsigned)LLEN;
        #pragma unroll
        for (int r = 0; r < 4; ++r) {
            a0[r] = fmaxf(a0[r], 0.f);
            a1[r] = fmaxf(a1[r], 0.f);
            if (EDGE) { a0[r] = ok ? a0[r] : 0.f; a1[r] = ok ? a1[r] : 0.f; }
        }
        if (!LAST) {
            bf16x4 p0, p1;
            #pragma unroll
            for (int r = 0; r < 4; ++r) { p0[r] = (__bf16)a0[r]; p1[r] = (__bf16)a1[r]; }
            *reinterpret_cast<bf16x4*>(&bout[o * RSTR + co0]) = p0;
            *reinterpret_cast<bf16x4*>(&bout[o * RSTR + 16 + co0]) = p1;
        } else {
            #pragma unroll
            for (int r = 0; r < 4; ++r) { vs[r] += a0[r]; vs[4 + r] += a1[r]; }
        }
    }
}

template<bool EDGE>
__device__ __forceinline__ void conv_body(
        const float* __restrict__ cin, const float* __restrict__ xin,
        const unsigned short* __restrict__ wf,
        const float* __restrict__ b0p, const float* __restrict__ bhp,
        __bf16* __restrict__ bufA, __bf16* __restrict__ bufB,
        int b, int gb, int lane, float* __restrict__ vs) {
    // ---- stage: lane p = row p. 24 coalesced scalar loads ARE the transpose.
    if (lane < SROWS) {
        const int p = lane;
        int g = gb - 4 + p;
        int gc = g;
        bool ok = true;
        if (EDGE) { gc = min(max(g, 0), LLEN - 1); ok = (g == gc); }
        const float* cbp = cin + (size_t)b * CCOND * LLEN + gc;
        const float* xbp = xin + (size_t)b * CX * LLEN + gc;
        float v[CIN0];
        #pragma unroll
        for (int ch = 0; ch < CCOND; ++ch) v[ch] = cbp[(size_t)ch * LLEN];
        #pragma unroll
        for (int ch = 0; ch < CX; ++ch) v[CCOND + ch] = xbp[(size_t)ch * LLEN];
        if (EDGE) {
            #pragma unroll
            for (int ch = 0; ch < CIN0; ++ch) v[ch] = ok ? v[ch] : 0.f;
        }
        bf16x8 pk0, pk1, pk2;
        #pragma unroll
        for (int j = 0; j < 8; ++j) {
            pk0[j] = (__bf16)v[j];
            pk1[j] = (__bf16)v[8 + j];
            pk2[j] = (__bf16)v[16 + j];
        }
        *reinterpret_cast<bf16x8*>(&bufA[p * RSTR])      = pk0;
        *reinterpret_cast<bf16x8*>(&bufA[p * RSTR + 8])  = pk1;
        *reinterpret_cast<bf16x8*>(&bufA[p * RSTR + 16]) = pk2;
        *reinterpret_cast<uint4*>(&bufA[p * RSTR + 24])  = make_uint4(0, 0, 0, 0);
    }
    WAVE_SYNC();

    const int s0[4] = {1, 17, 33, 39};
    const int s1[4] = {2, 18, 34, 38};
    const int s2[4] = {3, 19, 35, 37};
    const int s3[3] = {4, 20, 36};
    wconv_layer<4, 0, EDGE>(bufA, bufB, wf,        b0p,      s0, gb, lane, vs);
    WAVE_SYNC();
    wconv_layer<4, 0, EDGE>(bufB, bufA, wf + 3072, bhp,      s1, gb, lane, vs);
    WAVE_SYNC();
    wconv_layer<4, 0, EDGE>(bufA, bufB, wf + 6144, bhp + 32, s2, gb, lane, vs);
    WAVE_SYNC();
    wconv_layer<3, 1, EDGE>(bufB, bufA, wf + 9216, bhp + 64, s3, gb, lane, vs);
}

__global__ __launch_bounds__(256, 4) void conv_kernel(
        const float* __restrict__ cin,   // [B][16][L]
        const float* __restrict__ xin,   // [B][8][L]
        const unsigned short* __restrict__ wf,  // this t: [4][3][2][64][8]
        const float* __restrict__ b0p,   // [32]   (this t)
        const float* __restrict__ bhp,   // [3][32](this t)
        float* __restrict__ hbar) {      // [B][32] sums (atomic)
    __shared__ __align__(16) __bf16 lds[4][2][LWORDS];
    __shared__ float psum[4][HID];

    const int tid = threadIdx.x;
    const int lane = tid & 63, wv = tid >> 6;
    const int b = blockIdx.y;
    const int gb = blockIdx.x * (4 * WPW) + wv * WPW;
    const int prow = lane & 15, grp = lane >> 4;

    __bf16* bufA = &lds[wv][0][0];
    __bf16* bufB = &lds[wv][1][0];

    float vs[8] = {0.f, 0.f, 0.f, 0.f, 0.f, 0.f, 0.f, 0.f};
    const bool edge = (gb < 4) || (gb + SROWS - 4 > LLEN);
    if (edge)
        conv_body<true >(cin, xin, wf, b0p, bhp, bufA, bufB, b, gb, lane, vs);
    else
        conv_body<false>(cin, xin, wf, b0p, bhp, bufA, bufB, b, gb, lane, vs);

    // reduce vs over the 16 position-lanes via DPP row rotations (VALU pipe)
    #pragma unroll
    for (int r = 0; r < 8; ++r) {
        vs[r] += dpp_movf<RROR8>(vs[r]);
        vs[r] += dpp_movf<RROR4>(vs[r]);
        vs[r] += dpp_movf<RROR2>(vs[r]);
        vs[r] += dpp_movf<RROR1>(vs[r]);
    }
    const int co0 = grp * 4;
    if (prow == 0) {
        #pragma unroll
        for (int r = 0; r < 4; ++r) {
            psum[wv][co0 + r] = vs[r];
            psum[wv][16 + co0 + r] = vs[4 + r];
        }
    }
    __syncthreads();
    if (tid < HID) {
        float s = psum[0][tid] + psum[1][tid] + psum[2][tid] + psum[3][tid];
        atomicAdd(&hbar[b * HID + tid], s);
    }
}

// ---------------------------------------------------------------- RQS inverse
__device__ __forceinline__ float softplusf(float v) {
    return fmaxf(v, 0.f) + log1pf(expf(-fabsf(v)));
}

// Fused spline-prep + inverse. Per block: lanes 0..22 compute the 23 conv-out
// params (dot with mean-h); threads 0/64/128 (three waves, concurrent) build
// knot arrays into shared spl[43]; then 16 elements/thread inverse pass.
// spl layout: cw[0..8], ch[9..17], wd[18..25], hg[26..33], dv[34..42]
__device__ __forceinline__ void rqs_elem(
        const float* cw, const float* chv, const float* wd,
        const float* hg, const float* dv,
        float y, float& ov, float& ldsum) {
    bool inside = fabsf(y) <= 3.0f;
    float yc = fminf(fmaxf(y, -3.f), 3.f);

    float icw = cw[0], iw = wd[0], ich = chv[0], ih = hg[0];
    float dk = dv[0], dk1 = dv[1];
    #pragma unroll
    for (int k = 1; k < 8; k++) {
        bool c = yc >= chv[k];
        icw = c ? cw[k]  : icw;
        iw  = c ? wd[k]  : iw;
        ich = c ? chv[k] : ich;
        ih  = c ? hg[k]  : ih;
        dk  = c ? dv[k]  : dk;
        dk1 = c ? dv[k + 1] : dk1;
    }
    float s  = ih * __builtin_amdgcn_rcpf(iw);
    float dy = yc - ich;
    float t1 = dk + dk1 - 2.f * s;
    float a  = ih * (s - dk) + dy * t1;
    float bq = ih * dk - dy * t1;
    float cq = -s * dy;
    float disc = fmaxf(bq * bq - 4.f * a * cq, 0.f);
    float den  = -bq - __builtin_amdgcn_sqrtf(disc);
    float root = (2.f * cq) * __builtin_amdgcn_rcpf(den);
    float om = 1.f - root;
    float outv  = fmaf(root, iw, icw);
    float denom = fmaf(t1 * root, om, s);
    float dnum  = s * s * (dk1 * root * root + 2.f * s * root * om + dk * om * om);
    float ld = (2.f * __builtin_amdgcn_logf(denom) - __builtin_amdgcn_logf(dnum))
               * 0.69314718055994531f;
    ov = inside ? outv : y;
    ldsum += inside ? ld : 0.f;
}

__global__ __launch_bounds__(256) void rqs_kernel(
        const float* __restrict__ hbar,    // [B][32] sums (this t)
        const float* __restrict__ w_out,   // [184][32] (this t)
        const float* __restrict__ b_out,   // [184]     (this t)
        const float* __restrict__ xin,
        float* __restrict__ xout,
        float* __restrict__ logdet) {
    __shared__ float pj[PDIM];
    __shared__ float spl[43];
    __shared__ float red[4];
    const int bc = blockIdx.y;
    const int b = bc >> 3, c = bc & 7;
    const int tid = threadIdx.x;

    // ---- params: 23 dot-products across lanes 0..22
    if (tid < PDIM) {
        int cp = c * PDIM + tid;
        float acc = b_out[cp];
        const float* wrow = w_out + cp * HID;
        const float* hb = hbar + b * HID;
        const float invL = 1.0f / (float)LLEN;
        #pragma unroll
        for (int h = 0; h < HID; h++) acc = fmaf(wrow[h], hb[h] * invL, acc);
        pj[tid] = acc;
    }
    __syncthreads();
    // ---- knot building on three separate waves (concurrent)
    if (tid == 0) {                       // widths -> cw, wd
        float mx = pj[0];
        #pragma unroll
        for (int k = 1; k < 8; k++) mx = fmaxf(mx, pj[k]);
        float e[8], se = 0.f;
        #pragma unroll
        for (int k = 0; k < 8; k++) { e[k] = expf(pj[k] - mx); se += e[k]; }
        float inv = 1.f / se, cum = 0.f, prev = -3.f;
        spl[0] = -3.f;
        #pragma unroll
        for (int k = 0; k < 8; k++) {
            float wk = 1e-3f + (1.f - 8e-3f) * (e[k] * inv);
            cum += wk;
            float nk = 6.f * cum - 3.f;
            spl[k + 1] = nk;
            spl[18 + k] = nk - prev;
            prev = nk;
        }
    } else if (tid == 64) {               // heights -> ch, hg
        float mx = pj[8];
        #pragma unroll
        for (int k = 1; k < 8; k++) mx = fmaxf(mx, pj[8 + k]);
        float e[8], se = 0.f;
        #pragma unroll
        for (int k = 0; k < 8; k++) { e[k] = expf(pj[8 + k] - mx); se += e[k]; }
        float inv = 1.f / se, cum = 0.f, prev = -3.f;
        spl[9] = -3.f;
        #pragma unroll
        for (int k = 0; k < 8; k++) {
            float hk = 1e-3f + (1.f - 8e-3f) * (e[k] * inv);
            cum += hk;
            float nk = 6.f * cum - 3.f;
            spl[10 + k] = nk;
            spl[26 + k] = nk - prev;
            prev = nk;
        }
    } else if (tid == 128) {              // derivatives (boundary = 1)
        spl[34] = 1.f;
        #pragma unroll
        for (int k = 0; k < 7; k++) spl[35 + k] = 1e-3f + softplusf(pj[16 + k]);
        spl[42] = 1.f;
    }
    __syncthreads();

    float cw[9], chv[9], wd[8], hg[8], dv[9];
    #pragma unroll
    for (int k = 0; k < 9; k++) cw[k] = spl[k];
    #pragma unroll
    for (int k = 0; k < 9; k++) chv[k] = spl[9 + k];
    #pragma unroll
    for (int k = 0; k < 8; k++) wd[k] = spl[18 + k];
    #pragma unroll
    for (int k = 0; k < 8; k++) hg[k] = spl[26 + k];
    #pragma unroll
    for (int k = 0; k < 9; k++) dv[k] = spl[34 + k];

    size_t base = (size_t)bc * LLEN + (size_t)blockIdx.x * 4096 + (size_t)tid * 4;
    float4 y4[4];
    #pragma unroll
    for (int q = 0; q < 4; ++q)
        y4[q] = *reinterpret_cast<const float4*>(xin + base + q * 1024);

    float ldsum = 0.f;
    float4 o4[4];
    #pragma unroll
    for (int q = 0; q < 4; ++q) {
        rqs_elem(cw, chv, wd, hg, dv, y4[q].x, o4[q].x, ldsum);
        rqs_elem(cw, chv, wd, hg, dv, y4[q].y, o4[q].y, ldsum);
        rqs_elem(cw, chv, wd, hg, dv, y4[q].z, o4[q].z, ldsum);
        rqs_elem(cw, chv, wd, hg, dv, y4[q].w, o4[q].w, ldsum);
    }
    #pragma unroll
    for (int q = 0; q < 4; ++q)
        *reinterpret_cast<float4*>(xout + base + q * 1024) = o4[q];

    #pragma unroll
    for (int off = 32; off > 0; off >>= 1) ldsum += __shfl_xor(ldsum, off, 64);
    if ((tid & 63) == 0) red[tid >> 6] = ldsum;
    __syncthreads();
    if (tid == 0) {
        float sb = red[0] + red[1] + red[2] + red[3];
        atomicAdd(&logdet[bc >> 3], sb * (1.0f / (float)LLEN));
    }
}

// ---------------------------------------------------------------- launch
extern "C" void kernel_launch(void* const* d_in, const int* in_sizes, int n_in,
                              void* d_out, int out_size, void* d_ws, size_t ws_size,
                              hipStream_t stream) {
    const float* cin   = (const float*)d_in[1];
    const float* noise = (const float*)d_in[2];
    const float* w0    = (const float*)d_in[3];
    const float* b0    = (const float*)d_in[4];
    const float* wh    = (const float*)d_in[5];
    const float* bh    = (const float*)d_in[6];
    const float* w_out = (const float*)d_in[7];
    const float* b_out = (const float*)d_in[8];

    float* xout   = (float*)d_out;                       // [128*8*8192]
    float* logdet = xout + (size_t)BATCH * CX * LLEN;    // [128]

    float* ws     = (float*)d_ws;
    float* hbar0  = ws;                                  // 4096 floats
    float* hbar1  = ws + 4096;                           // 4096 floats
    unsigned short* wf = (unsigned short*)(ws + 8192);   // 24576 ushorts

    init_kernel<<<96, 256, 0, stream>>>(w0, wh, wf, ws, logdet);

    for (int t = 0; t < NSTEP; t++) {
        const float* xcur = (t == 0) ? noise : xout;
        float* hbar = (t == 0) ? hbar0 : hbar1;
        conv_kernel<<<dim3(GRIDX, BATCH), 256, 0, stream>>>(
            cin, xcur,
            wf + t * 12288, b0 + t * HID, bh + t * 3 * HID,
            hbar);
        rqs_kernel<<<dim3(LLEN / 4096, BATCH * CX), 256, 0, stream>>>(
            hbar, w_out + t * POUT * HID, b_out + t * POUT,
            xcur, xout, logdet);
    }
}